// Round 6
// baseline (88.336 us; speedup 1.0000x reference)
//
#include <hip/hip_runtime.h>
#include <cmath>

#define EPSN 1e-12f
#define CHUNK 128
#define NCH 128          // Y / CHUNK for Y=16384
#define NTL 128          // threads in k_combine
#define MAPCAP 16        // >= per_item (10)

__device__ __forceinline__ void amax_combine(float& v, int& i, float ov, int oi) {
    // jnp.argmax semantics: max value, first (lowest) index on ties
    if (ov > v || (ov == v && oi < i)) { v = ov; i = oi; }
}
__device__ __forceinline__ void wave_amax(float& v, int& i) {
    for (int off = 32; off; off >>= 1) {
        float a = __shfl_down(v, off, 64);
        int b = __shfl_down(i, off, 64);
        amax_combine(v, i, a, b);
    }
}

// ---------------------------------------------------------------------------
// k_prep: z2y row stats (blocks [0,NBZ)), y2z row norms ([NBZ,NBZ+Z)),
// x2y dot+norm2 ([NBZ+Z, NBZ+Z+Y)), ||x||^2 + cnt=0 (last block).
__global__ __launch_bounds__(256) void k_prep(
    const float* __restrict__ x2y, const float* __restrict__ z2y,
    const float* __restrict__ y2z, const int* __restrict__ zptr,
    const float* __restrict__ x,
    float* __restrict__ dotx, float* __restrict__ nw2,
    float* __restrict__ valz, float* __restrict__ nz2,
    float* __restrict__ nry, float* __restrict__ xn2, int* __restrict__ cnti,
    int X, int Y, int Z)
{
    const int bid = blockIdx.x;
    const int NBZ = Y / 4;
    const int tid = threadIdx.x;
    const int lane = tid & 63, wv = tid >> 6;
    if (bid < NBZ) {
        const int zv = zptr[0];
        const int row = bid * 4 + wv;
        const float* r = z2y + (size_t)row * Z;
        float q = 0.f, v = 0.f;
        for (int j = lane; j < Z; j += 64) {
            float e = r[j];
            q += e * e;
            if (j == zv) v = e;
        }
        for (int off = 32; off; off >>= 1) {
            q += __shfl_down(q, off, 64);
            v += __shfl_down(v, off, 64);
        }
        if (lane == 0) { nz2[row] = q; valz[row] = v; }
    } else if (bid < NBZ + Z) {
        const int row = bid - NBZ;
        const float4* r4 = (const float4*)(y2z + (size_t)row * Y);
        float q = 0.f;
        for (int i = tid; i < (Y >> 2); i += 256) {
            float4 w = r4[i];
            q += w.x*w.x + w.y*w.y + w.z*w.z + w.w*w.w;
        }
        for (int off = 32; off; off >>= 1) q += __shfl_down(q, off, 64);
        __shared__ float sq[4];
        if (lane == 0) sq[wv] = q;
        __syncthreads();
        if (tid == 0) nry[row] = sq[0] + sq[1] + sq[2] + sq[3];
    } else if (bid < NBZ + Z + Y) {
        const int row = bid - NBZ - Z;
        const float4* w4 = (const float4*)(x2y + (size_t)row * X);
        const float4* x4 = (const float4*)x;
        float d = 0.f, q = 0.f;
        for (int i = tid; i < (X >> 2); i += 256) {
            float4 w = w4[i]; float4 xx = x4[i];
            d += w.x*xx.x + w.y*xx.y + w.z*xx.z + w.w*xx.w;
            q += w.x*w.x + w.y*w.y + w.z*w.z + w.w*w.w;
        }
        for (int off = 32; off; off >>= 1) {
            d += __shfl_down(d, off, 64);
            q += __shfl_down(q, off, 64);
        }
        __shared__ float sd[4], sq2[4];
        if (lane == 0) { sd[wv] = d; sq2[wv] = q; }
        __syncthreads();
        if (tid == 0) {
            dotx[row] = sd[0] + sd[1] + sd[2] + sd[3];
            nw2[row]  = sq2[0] + sq2[1] + sq2[2] + sq2[3];
        }
    } else {
        // ||x||^2 and init young-counter
        const float4* x4 = (const float4*)x;
        float q = 0.f;
        for (int i = tid; i < (X >> 2); i += 256) {
            float4 xx = x4[i];
            q += xx.x*xx.x + xx.y*xx.y + xx.z*xx.z + xx.w*xx.w;
        }
        for (int off = 32; off; off >>= 1) q += __shfl_down(q, off, 64);
        __shared__ float sq3[4];
        if (lane == 0) sq3[wv] = q;
        __syncthreads();
        if (tid == 0) { xn2[0] = sq3[0]+sq3[1]+sq3[2]+sq3[3]; cnti[0] = 0; }
    }
}

// ---------------------------------------------------------------------------
// k_combine: per-neuron math + per-chunk argmax stats + per-chunk candidate
// ORIGINAL state (thr/age/valz/nz2/y2z/cA) so k_loop needs no gathers.
__global__ __launch_bounds__(NTL) void k_combine(
    const float* __restrict__ age_y_in, const float* __restrict__ thr_in,
    const float* __restrict__ y2z, const int* __restrict__ zptr,
    const float* __restrict__ dotx, const float* __restrict__ nw2,
    const float* __restrict__ valz, const float* __restrict__ nz2,
    const float* __restrict__ xn2,
    float* __restrict__ yp_ws, float* __restrict__ cA_ws,
    float* __restrict__ chv, int* __restrict__ chi,
    float* __restrict__ chcv, int* __restrict__ chci,
    float* __restrict__ cthr, float* __restrict__ cage,
    float* __restrict__ cvz, float* __restrict__ cnz,
    float* __restrict__ cyz, float* __restrict__ ccc,
    int* __restrict__ cnti, int Y)
{
    const int b = blockIdx.x, t = threadIdx.x;
    const int e = b * CHUNK + t;
    const int lane = t & 63, wv = t >> 6;
    const int zv = zptr[0];
    const float xn = fmaxf(sqrtf(xn2[0]), EPSN);
    const float vz_e = valz[e], nz_e = nz2[e];
    const float thr_e = thr_in[e];
    const float yz_e = y2z[(size_t)zv * Y + e];
    const float c = dotx[e] / (fmaxf(sqrtf(nw2[e]), EPSN) * xn);
    const float s = vz_e / fmaxf(sqrtf(nz_e), EPSN);
    const float ypv = 0.5f * (c + s);
    const float agev = age_y_in[e];
    const int young = agev < 1.0f;
    cA_ws[e] = c;
    yp_ws[e] = ypv;
    float v1 = ypv; int i1 = e;
    float v2 = c * (young ? 0.0f : 1.0f); int i2 = e;   // jnp multiply-mask (±0)
    int yc = young;
    wave_amax(v1, i1);
    wave_amax(v2, i2);
    for (int off = 32; off; off >>= 1) yc += __shfl_down(yc, off, 64);
    __shared__ float s1v[2]; __shared__ int s1i[2];
    __shared__ float s2v[2]; __shared__ int s2i[2];
    __shared__ int syc[2]; __shared__ int sh_c1;
    if (lane == 0) { s1v[wv] = v1; s1i[wv] = i1; s2v[wv] = v2; s2i[wv] = i2; syc[wv] = yc; }
    __syncthreads();
    if (t == 0) {
        float a = s1v[0]; int ai = s1i[0];
        amax_combine(a, ai, s1v[1], s1i[1]);
        float bmv = s2v[0]; int bmi = s2i[0];
        amax_combine(bmv, bmi, s2v[1], s2i[1]);
        chv[b] = a; chi[b] = ai; chcv[b] = bmv; chci[b] = bmi;
        sh_c1 = ai;
        atomicAdd(cnti, syc[0] + syc[1]);
    }
    __syncthreads();
    if (e == sh_c1) {   // candidate thread exports its original state
        cthr[b] = thr_e; cage[b] = agev; cvz[b] = vz_e;
        cnz[b] = nz_e;   cyz[b] = yz_e;  ccc[b] = c;
    }
}

// ---------------------------------------------------------------------------
// Uniform winner update: executes identically on all 64 lanes (all inputs
// wave-uniform). Maps live in per-lane registers with fully-unrolled
// static-index access (rule #20: no runtime-indexed register arrays).
#define UPD(WIN, Gthr, Gage, Gvz, Gnz, Gy2z, Gc) do { \
    const int w_ = (WIN); \
    float age_o = (Gage), thr_o = (Gthr), c_o = (Gc); \
    float s_o = (Gvz) / fmaxf(sqrtf((Gnz)), EPSN); \
    int e_ = -1; \
    _Pragma("unroll") \
    for (int k_ = 0; k_ < MAPCAP; ++k_) if (wmI[k_] == w_) { \
        age_o = wmAge[k_]; thr_o = wmThr[k_]; s_o = wmS[k_]; c_o = wmC[k_]; e_ = k_; } \
    const float lr_ = 1.f/(age_o+1.f), om_ = 1.f-lr_; \
    const float cn_ = (om_*c_o+lr_)/fmaxf(sqrtf(om_*om_+lr_*lr_+2.f*lr_*om_*c_o), EPSN); \
    const float sn_ = (om_*s_o+lr_)/fmaxf(sqrtf(om_*om_+lr_*lr_+2.f*lr_*om_*s_o), EPSN); \
    if (e_ < 0) { e_ = wmn; wmn++; } \
    _Pragma("unroll") \
    for (int k_ = 0; k_ < MAPCAP; ++k_) if (k_ == e_) { \
        wmI[k_] = w_; wmAge[k_] = age_o + 1.f; wmThr[k_] = lr_*r0 + om_*thr_o; \
        wmS[k_] = sn_; wmC[k_] = cn_; wmYp[k_] = 0.5f*(cn_+sn_); } \
    if (age_o < 1.f && age_o + 1.f >= 1.f) cnt--; \
    { const int cw_ = (w_) >> 7; \
      if (lane == (cw_ & 63)) { \
        if (cw_ & 64) amax_combine(chc1, chcI1, cn_, w_); \
        else          amax_combine(chc0, chcI0, cn_, w_); } } \
    const float L_ = fmaxf(sqrtf(beta*beta*N0sq + 2.f*beta*Aacc + Bacc), EPSN); \
    beta /= L_; Aacc /= L_; Bacc /= (L_*L_); \
    _Pragma("unroll") \
    for (int k_ = 0; k_ < MAPCAP; ++k_) ymG[k_] /= L_; \
    const float zlr_ = 1.f/(agez+1.f), oz_ = 1.f-zlr_; \
    beta *= oz_; Aacc *= oz_; Bacc *= oz_*oz_; \
    _Pragma("unroll") \
    for (int k_ = 0; k_ < MAPCAP; ++k_) ymG[k_] *= oz_; \
    int q_ = -1; \
    _Pragma("unroll") \
    for (int k_ = 0; k_ < MAPCAP; ++k_) if (ymI[k_] == w_) q_ = k_; \
    if (q_ < 0) { q_ = ymn; ymn++; \
        _Pragma("unroll") \
        for (int k_ = 0; k_ < MAPCAP; ++k_) if (k_ == q_) { \
            ymI[k_] = w_; ymG[k_] = 0.f; ymV0[k_] = (Gy2z); } } \
    float gold_ = 0.f, v0_ = 0.f; \
    _Pragma("unroll") \
    for (int k_ = 0; k_ < MAPCAP; ++k_) if (k_ == q_) { gold_ = ymG[k_]; v0_ = ymV0[k_]; } \
    Bacc += 2.f*zlr_*gold_ + zlr_*zlr_; \
    Aacc += zlr_*v0_; \
    _Pragma("unroll") \
    for (int k_ = 0; k_ < MAPCAP; ++k_) if (k_ == q_) ymG[k_] = gold_ + zlr_; \
    agez += 1.f; \
    win = w_; \
} while (0)

// Single-wave, zero-barrier, zero-LDS train loop.
__global__ __launch_bounds__(64) void k_loop(
    const int* __restrict__ zptr, const int* __restrict__ pitem,
    const float* __restrict__ y2z,
    const float* __restrict__ age_y_in, const float* __restrict__ age_z_in,
    const float* __restrict__ thr_in,
    const float* __restrict__ valz, const float* __restrict__ nz2,
    const float* __restrict__ nry,
    const float* __restrict__ yp_ws, const float* __restrict__ cA_ws,
    const float* __restrict__ chv_g, const int* __restrict__ chi_g,
    const float* __restrict__ chcv_g, const int* __restrict__ chci_g,
    const float* __restrict__ cthr, const float* __restrict__ cage,
    const float* __restrict__ cvz, const float* __restrict__ cnz,
    const float* __restrict__ cyz, const float* __restrict__ ccc,
    const int* __restrict__ cnti,
    float* __restrict__ out, int Y, int Z)
{
    const int lane = threadIdx.x;
    const int zv = zptr[0];
    const float* __restrict__ y2zrow = y2z + (size_t)zv * Y;

    // chunk stats: 2 chunks per lane, registers
    float chv0 = chv_g[lane], chv1 = chv_g[lane + 64];
    int   chi0 = chi_g[lane], chi1 = chi_g[lane + 64];
    float chc0 = chcv_g[lane], chc1 = chcv_g[lane + 64];
    int   chcI0 = chci_g[lane], chcI1 = chci_g[lane + 64];
    // per-chunk candidate ORIGINAL state (coalesced from k_combine)
    float pthr0 = cthr[lane], pthr1 = cthr[lane + 64];
    float page0 = cage[lane], page1 = cage[lane + 64];
    float pvz0  = cvz[lane],  pvz1  = cvz[lane + 64];
    float pnz0  = cnz[lane],  pnz1  = cnz[lane + 64];
    float pyz0  = cyz[lane],  pyz1  = cyz[lane + 64];
    float pca0  = ccc[lane],  pca1  = ccc[lane + 64];

    // uniform scalar state (replicated on all lanes)
    int cnt = cnti[0];
    float N0sq = nry[zv], agez = age_z_in[zv];
    float beta = 1.f, Aacc = 0.f, Bacc = 0.f;
    int wmn = 0, ymn = 0;
    int   wmI[MAPCAP]; float wmAge[MAPCAP], wmThr[MAPCAP], wmS[MAPCAP], wmC[MAPCAP], wmYp[MAPCAP];
    int   ymI[MAPCAP]; float ymG[MAPCAP], ymV0[MAPCAP];
#pragma unroll
    for (int k = 0; k < MAPCAP; ++k) {
        wmI[k] = -1; wmAge[k] = 0.f; wmThr[k] = 0.f; wmS[k] = 0.f; wmC[k] = 0.f; wmYp[k] = 0.f;
        ymI[k] = -1; ymG[k] = 0.f; ymV0[k] = 0.f;
    }

    const int PI = pitem[0];
    for (int t = 0; t < PI; ++t) {
        // global argmax over 128 chunk maxima (pure shuffle)
        float v = chv0; int i = chi0;
        amax_combine(v, i, chv1, chi1);
        wave_amax(v, i);
        const float r0 = __shfl(v, 0);
        const int   i0 = __shfl(i, 0);
        // broadcast candidate slot state for chunk ts = i0>>7
        const int ts = i0 >> 7;
        const int sl = ts & 63;
        const bool hi = (ts & 64) != 0;
        const float bthr = __shfl(hi ? pthr1 : pthr0, sl);
        const float bage = __shfl(hi ? page1 : page0, sl);
        const float bvz  = __shfl(hi ? pvz1  : pvz0,  sl);
        const float bnz  = __shfl(hi ? pnz1  : pnz0,  sl);
        const float byz  = __shfl(hi ? pyz1  : pyz0,  sl);
        const float bca  = __shfl(hi ? pca1  : pca0,  sl);
        // keep test with wm override
        float age0 = bage, thr0 = bthr;
#pragma unroll
        for (int k = 0; k < MAPCAP; ++k)
            if (wmI[k] == i0) { age0 = wmAge[k]; thr0 = wmThr[k]; }
        const bool keep = (r0 > thr0) || (age0 < 1.f);
        int win;
        if (keep) {
            UPD(i0, bthr, bage, bvz, bnz, byz, bca);
        } else {
            // rare slow path: full masked sweep with wm overrides
            float mv = -INFINITY; int mi = 0;
            for (int e = lane; e < Y; e += 64) {
                float vv = yp_ws[e];
                float ag = age_y_in[e];
#pragma unroll
                for (int k = 0; k < MAPCAP; ++k)
                    if (wmI[k] == e) { vv = wmYp[k]; ag = wmAge[k]; }
                const float m = vv * (ag < 1.f ? 1.f : 0.f);   // jnp ±0 mask
                amax_combine(mv, mi, m, e);
            }
            wave_amax(mv, mi);
            const int alt = __shfl(mi, 0);
            if (cnt > 0) {
                const float gthr = thr_in[alt], gage = age_y_in[alt];
                const float gvz = valz[alt],   gnz = nz2[alt];
                const float gy  = y2zrow[alt], gc = cA_ws[alt];
                UPD(alt, gthr, gage, gvz, gnz, gy, gc);
            } else {
                UPD(i0, bthr, bage, bvz, bnz, byz, bca);
            }
        }
        // rescan winner's chunk (128 elems, wm-overridden), update chv regs
        const int cw = win >> 7;
        const int base = cw * CHUNK;
        float vA = yp_ws[base + lane];
        float vB = yp_ws[base + 64 + lane];
        int iA = base + lane, iB = base + 64 + lane;
#pragma unroll
        for (int k = 0; k < MAPCAP; ++k) {
            if (wmI[k] == iA) vA = wmYp[k];
            if (wmI[k] == iB) vB = wmYp[k];
        }
        amax_combine(vA, iA, vB, iB);
        wave_amax(vA, iA);
        const float nv = __shfl(vA, 0);
        const int   ni = __shfl(iA, 0);
        // refill candidate slot with ni's ORIGINAL state (uniform broadcast loads)
        const float nthr = thr_in[ni], nage = age_y_in[ni];
        const float nvz = valz[ni],   nnz = nz2[ni];
        const float nyz = y2zrow[ni], nca = cA_ws[ni];
        if (lane == (cw & 63)) {
            if (cw & 64) {
                chv1 = nv; chi1 = ni;
                pthr1 = nthr; page1 = nage; pvz1 = nvz; pnz1 = nnz; pyz1 = nyz; pca1 = nca;
            } else {
                chv0 = nv; chi0 = ni;
                pthr0 = nthr; page0 = nage; pvz0 = nvz; pnz0 = nnz; pyz0 = nyz; pca0 = nca;
            }
        }
    }

    // ---- Final: argmax over maintained cA*flag chunk maxima
    float fv = chc0; int fi = chcI0;
    amax_combine(fv, fi, chc1, chcI1);
    wave_amax(fv, fi);
    const int winf = __shfl(fi, 0);
    const float actn = (float)Y - (float)cnt;
    const float L = fmaxf(sqrtf(beta*beta*N0sq + 2.f*beta*Aacc + Bacc), EPSN);
    float g = 0.f, v0wf = y2zrow[winf];   // uniform load; map overrides below
#pragma unroll
    for (int k = 0; k < MAPCAP; ++k)
        if (ymI[k] == winf) { g = ymG[k]; v0wf = ymV0[k]; }
    const float outz = (beta * v0wf + g) / L;
    for (int e = lane; e < Z; e += 64) {
        const float o = (e == zv) ? outz
            : y2z[(size_t)e * Y + winf] / fmaxf(sqrtf(nry[e]), EPSN);
        out[e] = o;
    }
    if (lane == 0) out[Z] = actn;
}

extern "C" void kernel_launch(void* const* d_in, const int* in_sizes, int n_in,
                              void* d_out, int out_size, void* d_ws, size_t ws_size,
                              hipStream_t stream) {
    const float* x    = (const float*)d_in[0];
    const int*   z    = (const int*)d_in[1];
    const int*   pit  = (const int*)d_in[2];
    const float* x2y  = (const float*)d_in[3];
    const float* z2y  = (const float*)d_in[4];
    const float* y2z  = (const float*)d_in[5];
    const float* agey = (const float*)d_in[6];
    const float* agez = (const float*)d_in[7];
    const float* thr  = (const float*)d_in[8];
    const int X = in_sizes[0];   // 4096
    const int Y = in_sizes[6];   // 16384
    const int Z = in_sizes[7];   // 100

    float* ws = (float*)d_ws;
    float* dotx = ws;                       // Y
    float* nw2  = ws + (size_t)Y;           // Y
    float* valz = ws + 2*(size_t)Y;         // Y
    float* nz2  = ws + 3*(size_t)Y;         // Y
    float* nry  = ws + 4*(size_t)Y;         // Z (padded to 128)
    float* xn2  = ws + 4*(size_t)Y + 128;   // 1
    int*   cnti = (int*)(ws + 4*(size_t)Y + 129);
    float* ypw  = ws + 4*(size_t)Y + 256;   // Y
    float* cAw  = ws + 5*(size_t)Y + 256;   // Y
    float* base6 = ws + 6*(size_t)Y + 256;
    float* chv  = base6;                    // NCH
    int*   chi  = (int*)(base6 + NCH);
    float* chcv = base6 + 2*NCH;
    int*   chci = (int*)(base6 + 3*NCH);
    float* cthr = base6 + 4*NCH;
    float* cage = base6 + 5*NCH;
    float* cvz  = base6 + 6*NCH;
    float* cnz  = base6 + 7*NCH;
    float* cyz  = base6 + 8*NCH;
    float* ccc  = base6 + 9*NCH;
    float* out  = (float*)d_out;

    const int NBZ = Y / 4;
    const int grid_prep = NBZ + Z + Y + 1;
    hipLaunchKernelGGL(k_prep, dim3(grid_prep), dim3(256), 0, stream,
                       x2y, z2y, y2z, z, x, dotx, nw2, valz, nz2, nry, xn2, cnti, X, Y, Z);
    hipLaunchKernelGGL(k_combine, dim3(Y / CHUNK), dim3(NTL), 0, stream,
                       agey, thr, y2z, z, dotx, nw2, valz, nz2, xn2,
                       ypw, cAw, chv, chi, chcv, chci,
                       cthr, cage, cvz, cnz, cyz, ccc, cnti, Y);
    hipLaunchKernelGGL(k_loop, dim3(1), dim3(64), 0, stream,
                       z, pit, y2z, agey, agez, thr, valz, nz2, nry,
                       ypw, cAw, chv, chi, chcv, chci,
                       cthr, cage, cvz, cnz, cyz, ccc, cnti, out, Y, Z);
}

// Round 7
// 74.580 us; speedup vs baseline: 1.1844x; 1.1844x over previous
//
#include <hip/hip_runtime.h>
#include <cmath>

#define EPSN 1e-12f
#define CHUNK 128
#define NCH 128          // Y / CHUNK for Y=16384
#define NTL 128          // threads in k_combine

__device__ __forceinline__ void amax_combine(float& v, int& i, float ov, int oi) {
    // jnp.argmax semantics: max value, first (lowest) index on ties
    if (ov > v || (ov == v && oi < i)) { v = ov; i = oi; }
}
__device__ __forceinline__ void wave_amax(float& v, int& i) {
    for (int off = 32; off; off >>= 1) {
        float a = __shfl_down(v, off, 64);
        int b = __shfl_down(i, off, 64);
        amax_combine(v, i, a, b);
    }
}

// ---------------------------------------------------------------------------
// k_prep: z2y row stats (blocks [0,NBZ)), y2z row norms ([NBZ,NBZ+Z)),
// x2y dot+norm2 ([NBZ+Z, NBZ+Z+Y)), ||x||^2 + cnt=0 (last block).
__global__ __launch_bounds__(256) void k_prep(
    const float* __restrict__ x2y, const float* __restrict__ z2y,
    const float* __restrict__ y2z, const int* __restrict__ zptr,
    const float* __restrict__ x,
    float* __restrict__ dotx, float* __restrict__ nw2,
    float* __restrict__ valz, float* __restrict__ nz2,
    float* __restrict__ nry, float* __restrict__ xn2, int* __restrict__ cnti,
    int X, int Y, int Z)
{
    const int bid = blockIdx.x;
    const int NBZ = Y / 4;
    const int tid = threadIdx.x;
    const int lane = tid & 63, wv = tid >> 6;
    if (bid < NBZ) {
        const int zv = zptr[0];
        const int row = bid * 4 + wv;
        const float* r = z2y + (size_t)row * Z;
        float q = 0.f, v = 0.f;
        for (int j = lane; j < Z; j += 64) {
            float e = r[j];
            q += e * e;
            if (j == zv) v = e;
        }
        for (int off = 32; off; off >>= 1) {
            q += __shfl_down(q, off, 64);
            v += __shfl_down(v, off, 64);
        }
        if (lane == 0) { nz2[row] = q; valz[row] = v; }
    } else if (bid < NBZ + Z) {
        const int row = bid - NBZ;
        const float4* r4 = (const float4*)(y2z + (size_t)row * Y);
        float q = 0.f;
        for (int i = tid; i < (Y >> 2); i += 256) {
            float4 w = r4[i];
            q += w.x*w.x + w.y*w.y + w.z*w.z + w.w*w.w;
        }
        for (int off = 32; off; off >>= 1) q += __shfl_down(q, off, 64);
        __shared__ float sq[4];
        if (lane == 0) sq[wv] = q;
        __syncthreads();
        if (tid == 0) nry[row] = sq[0] + sq[1] + sq[2] + sq[3];
    } else if (bid < NBZ + Z + Y) {
        const int row = bid - NBZ - Z;
        const float4* w4 = (const float4*)(x2y + (size_t)row * X);
        const float4* x4 = (const float4*)x;
        float d = 0.f, q = 0.f;
        for (int i = tid; i < (X >> 2); i += 256) {
            float4 w = w4[i]; float4 xx = x4[i];
            d += w.x*xx.x + w.y*xx.y + w.z*xx.z + w.w*xx.w;
            q += w.x*w.x + w.y*w.y + w.z*w.z + w.w*w.w;
        }
        for (int off = 32; off; off >>= 1) {
            d += __shfl_down(d, off, 64);
            q += __shfl_down(q, off, 64);
        }
        __shared__ float sd[4], sq2[4];
        if (lane == 0) { sd[wv] = d; sq2[wv] = q; }
        __syncthreads();
        if (tid == 0) {
            dotx[row] = sd[0] + sd[1] + sd[2] + sd[3];
            nw2[row]  = sq2[0] + sq2[1] + sq2[2] + sq2[3];
        }
    } else {
        // ||x||^2 and init young-counter
        const float4* x4 = (const float4*)x;
        float q = 0.f;
        for (int i = tid; i < (X >> 2); i += 256) {
            float4 xx = x4[i];
            q += xx.x*xx.x + xx.y*xx.y + xx.z*xx.z + xx.w*xx.w;
        }
        for (int off = 32; off; off >>= 1) q += __shfl_down(q, off, 64);
        __shared__ float sq3[4];
        if (lane == 0) sq3[wv] = q;
        __syncthreads();
        if (tid == 0) { xn2[0] = sq3[0]+sq3[1]+sq3[2]+sq3[3]; cnti[0] = 0; }
    }
}

// ---------------------------------------------------------------------------
// k_combine: per-neuron math -> LIVE state arrays + per-chunk argmax stats.
__global__ __launch_bounds__(NTL) void k_combine(
    const float* __restrict__ age_y_in, const float* __restrict__ thr_in,
    const float* __restrict__ dotx, const float* __restrict__ nw2,
    const float* __restrict__ valz, const float* __restrict__ nz2,
    const float* __restrict__ xn2,
    float* __restrict__ yp_live, float* __restrict__ cA_live,
    float* __restrict__ s_live, float* __restrict__ age_live,
    float* __restrict__ thr_live,
    float* __restrict__ chv, int* __restrict__ chi,
    float* __restrict__ chcv, int* __restrict__ chci,
    int* __restrict__ cnti)
{
    const int b = blockIdx.x, t = threadIdx.x;
    const int e = b * CHUNK + t;
    const int lane = t & 63, wv = t >> 6;
    const float xn = fmaxf(sqrtf(xn2[0]), EPSN);
    const float c = dotx[e] / (fmaxf(sqrtf(nw2[e]), EPSN) * xn);
    const float s = valz[e] / fmaxf(sqrtf(nz2[e]), EPSN);
    const float ypv = 0.5f * (c + s);
    const float agev = age_y_in[e];
    const int young = agev < 1.0f;
    cA_live[e] = c;
    yp_live[e] = ypv;
    s_live[e] = s;
    age_live[e] = agev;
    thr_live[e] = thr_in[e];
    float v1 = ypv; int i1 = e;
    float v2 = c * (young ? 0.0f : 1.0f); int i2 = e;   // jnp multiply-mask (±0)
    int yc = young;
    wave_amax(v1, i1);
    wave_amax(v2, i2);
    for (int off = 32; off; off >>= 1) yc += __shfl_down(yc, off, 64);
    __shared__ float s1v[2]; __shared__ int s1i[2];
    __shared__ float s2v[2]; __shared__ int s2i[2];
    __shared__ int syc[2];
    if (lane == 0) { s1v[wv] = v1; s1i[wv] = i1; s2v[wv] = v2; s2i[wv] = i2; syc[wv] = yc; }
    __syncthreads();
    if (t == 0) {
        float a = s1v[0]; int ai = s1i[0];
        amax_combine(a, ai, s1v[1], s1i[1]);
        float bmv = s2v[0]; int bmi = s2i[0];
        amax_combine(bmv, bmi, s2v[1], s2i[1]);
        chv[b] = a; chi[b] = ai; chcv[b] = bmv; chci[b] = bmi;
        atomicAdd(cnti, syc[0] + syc[1]);
    }
}

// ---------------------------------------------------------------------------
// Winner update. Runs uniformly on all 64 lanes. AGE/THR/CO/SO/Y0 are the
// winner's CURRENT live state (prefetched uniform loads). Live arrays are
// updated with all-lane uniform stores (same-thread store->load visibility).
// ym map is lane-distributed: slot k lives on lane k.
#define UPD(W, AGE, THR, CO, SO, Y0) do { \
    const int w_ = (W); \
    const float age_o = (AGE), thr_o = (THR), c_o = (CO), s_o = (SO); \
    const float lr_ = 1.f/(age_o+1.f), om_ = 1.f-lr_; \
    const float cn_ = (om_*c_o+lr_)/fmaxf(sqrtf(om_*om_+lr_*lr_+2.f*lr_*om_*c_o), EPSN); \
    const float sn_ = (om_*s_o+lr_)/fmaxf(sqrtf(om_*om_+lr_*lr_+2.f*lr_*om_*s_o), EPSN); \
    const float ypn_ = 0.5f*(cn_+sn_); \
    yp_live[w_] = ypn_; cA_live[w_] = cn_; s_live[w_] = sn_; \
    age_live[w_] = age_o + 1.f; thr_live[w_] = lr_*r0 + om_*thr_o; \
    if (age_o < 1.f && age_o + 1.f >= 1.f) cnt--; \
    { const int cw_ = w_ >> 7; \
      if (lane == (cw_ & 63)) { \
        if (cw_ & 64) amax_combine(chc1, chcI1, cn_, w_); \
        else          amax_combine(chc0, chcI0, cn_, w_); } } \
    const float L_ = fmaxf(sqrtf(beta*beta*N0sq + 2.f*beta*Aacc + Bacc), EPSN); \
    beta /= L_; Aacc /= L_; Bacc /= (L_*L_); ymG_l /= L_; \
    const float zlr_ = 1.f/(agez+1.f), oz_ = 1.f-zlr_; \
    beta *= oz_; Aacc *= oz_; Bacc *= oz_*oz_; ymG_l *= oz_; \
    unsigned long long qm_ = __ballot(ymI_l == w_); \
    int q_; \
    if (qm_ == 0ull) { \
        q_ = ymn; \
        if (lane == q_) { ymI_l = w_; ymG_l = 0.f; ymV0_l = (Y0); } \
        ymn++; \
    } else q_ = (int)__ffsll((long long)qm_) - 1; \
    const float gold_ = __shfl(ymG_l, q_); \
    const float v0_   = __shfl(ymV0_l, q_); \
    Bacc += 2.f*zlr_*gold_ + zlr_*zlr_; \
    Aacc += zlr_*v0_; \
    if (lane == q_) ymG_l = gold_ + zlr_; \
    agez += 1.f; \
    win = w_; ypnew = ypn_; \
} while (0)

// Single-wave, zero-barrier, zero-LDS train loop over live state arrays.
__global__ __launch_bounds__(64) void k_loop(
    const int* __restrict__ zptr, const int* __restrict__ pitem,
    const float* __restrict__ y2z,
    const float* __restrict__ age_z_in, const float* __restrict__ nry,
    float* __restrict__ yp_live, float* __restrict__ cA_live,
    float* __restrict__ s_live, float* __restrict__ age_live,
    float* __restrict__ thr_live,
    const float* __restrict__ chv_g, const int* __restrict__ chi_g,
    const float* __restrict__ chcv_g, const int* __restrict__ chci_g,
    const int* __restrict__ cnti,
    float* __restrict__ out, int Y, int Z)
{
    const int lane = threadIdx.x;
    const int zv = zptr[0];
    const float* __restrict__ y2zrow = y2z + (size_t)zv * Y;

    // chunk stats: 2 chunks per lane, registers
    float chv0 = chv_g[lane], chv1 = chv_g[lane + 64];
    int   chi0 = chi_g[lane], chi1 = chi_g[lane + 64];
    float chc0 = chcv_g[lane], chc1 = chcv_g[lane + 64];
    int   chcI0 = chci_g[lane], chcI1 = chci_g[lane + 64];

    // uniform scalar state (replicated on all lanes)
    int cnt = cnti[0];
    float N0sq = nry[zv], agez = age_z_in[zv];
    float beta = 1.f, Aacc = 0.f, Bacc = 0.f;
    // lane-distributed ym map (y2z row z: v = beta*v0 + sum_k g_k e_{I_k})
    int ymn = 0;
    int ymI_l = -1; float ymG_l = 0.f, ymV0_l = 0.f;

    const int PI = pitem[0];
    for (int t = 0; t < PI; ++t) {
        // (a) global argmax over 128 chunk maxima (pure shuffle)
        float v = chv0; int i = chi0;
        amax_combine(v, i, chv1, chi1);
        wave_amax(v, i);
        const float r0 = __shfl(v, 0);
        const int   i0 = __shfl(i, 0);
        // (b) prefetch i0's live state (uniform) + speculative rescan loads
        const float a_i0 = age_live[i0];
        const float t_i0 = thr_live[i0];
        const float c_i0 = cA_live[i0];
        const float s_i0 = s_live[i0];
        const float y_i0 = y2zrow[i0];
        const int base0 = (i0 >> 7) * CHUNK;
        const float rA = yp_live[base0 + lane];
        const float rB = yp_live[base0 + 64 + lane];
        // (c) keep test + update (wave-uniform control flow)
        const bool keep = (r0 > t_i0) || (a_i0 < 1.f);
        int win; float ypnew;
        if (keep) {
            UPD(i0, a_i0, t_i0, c_i0, s_i0, y_i0);
        } else {
            // rare slow path: full masked sweep over live arrays
            float mv = -INFINITY; int mi = 0;
            for (int e = lane; e < Y; e += 64) {
                const float vv = yp_live[e];
                const float ag = age_live[e];
                const float m = vv * (ag < 1.f ? 1.f : 0.f);   // jnp ±0 mask
                amax_combine(mv, mi, m, e);
            }
            wave_amax(mv, mi);
            const int alt = __shfl(mi, 0);
            if (cnt > 0) {
                const float a_a = age_live[alt], t_a = thr_live[alt];
                const float c_a = cA_live[alt],  s_a = s_live[alt];
                const float y_a = y2zrow[alt];
                UPD(alt, a_a, t_a, c_a, s_a, y_a);
            } else {
                UPD(i0, a_i0, t_i0, c_i0, s_i0, y_i0);
            }
        }
        // (d) rescan winner's chunk; winner element substituted from register
        const int cw = win >> 7;
        const int base = cw * CHUNK;
        float vA, vB;
        if (base == base0) { vA = rA; vB = rB; }
        else { vA = yp_live[base + lane]; vB = yp_live[base + 64 + lane]; }
        int iA = base + lane, iB = base + 64 + lane;
        if (iA == win) vA = ypnew;
        if (iB == win) vB = ypnew;
        amax_combine(vA, iA, vB, iB);
        wave_amax(vA, iA);
        const float nv = __shfl(vA, 0);
        const int   ni = __shfl(iA, 0);
        if (lane == (cw & 63)) {
            if (cw & 64) { chv1 = nv; chi1 = ni; }
            else         { chv0 = nv; chi0 = ni; }
        }
    }

    // ---- Final: argmax over maintained cA*activated chunk maxima
    float fv = chc0; int fi = chcI0;
    amax_combine(fv, fi, chc1, chcI1);
    wave_amax(fv, fi);
    const int winf = __shfl(fi, 0);
    const float actn = (float)Y - (float)cnt;
    const float L = fmaxf(sqrtf(beta*beta*N0sq + 2.f*beta*Aacc + Bacc), EPSN);
    float g = 0.f, v0wf;
    const unsigned long long fm = __ballot(ymI_l == winf);
    if (fm != 0ull) {
        const int k = (int)__ffsll((long long)fm) - 1;
        g = __shfl(ymG_l, k);
        v0wf = __shfl(ymV0_l, k);
    } else {
        v0wf = y2zrow[winf];
    }
    const float outz = (beta * v0wf + g) / L;
    for (int e = lane; e < Z; e += 64) {
        const float o = (e == zv) ? outz
            : y2z[(size_t)e * Y + winf] / fmaxf(sqrtf(nry[e]), EPSN);
        out[e] = o;
    }
    if (lane == 0) out[Z] = actn;
}

extern "C" void kernel_launch(void* const* d_in, const int* in_sizes, int n_in,
                              void* d_out, int out_size, void* d_ws, size_t ws_size,
                              hipStream_t stream) {
    const float* x    = (const float*)d_in[0];
    const int*   z    = (const int*)d_in[1];
    const int*   pit  = (const int*)d_in[2];
    const float* x2y  = (const float*)d_in[3];
    const float* z2y  = (const float*)d_in[4];
    const float* y2z  = (const float*)d_in[5];
    const float* agey = (const float*)d_in[6];
    const float* agez = (const float*)d_in[7];
    const float* thr  = (const float*)d_in[8];
    const int X = in_sizes[0];   // 4096
    const int Y = in_sizes[6];   // 16384
    const int Z = in_sizes[7];   // 100

    float* ws = (float*)d_ws;
    float* dotx = ws;                        // Y
    float* nw2  = ws + (size_t)Y;            // Y
    float* valz = ws + 2*(size_t)Y;          // Y
    float* nz2  = ws + 3*(size_t)Y;          // Y
    float* nry  = ws + 4*(size_t)Y;          // Z (padded to 128)
    float* xn2  = ws + 4*(size_t)Y + 128;    // 1
    int*   cnti = (int*)(ws + 4*(size_t)Y + 129);
    float* ypl  = ws + 4*(size_t)Y + 256;    // Y  (live)
    float* cAl  = ws + 5*(size_t)Y + 256;    // Y  (live)
    float* sl   = ws + 6*(size_t)Y + 256;    // Y  (live)
    float* agl  = ws + 7*(size_t)Y + 256;    // Y  (live)
    float* thl  = ws + 8*(size_t)Y + 256;    // Y  (live)
    float* base9 = ws + 9*(size_t)Y + 256;
    float* chv  = base9;                     // NCH
    int*   chi  = (int*)(base9 + NCH);
    float* chcv = base9 + 2*NCH;
    int*   chci = (int*)(base9 + 3*NCH);
    float* out  = (float*)d_out;

    const int NBZ = Y / 4;
    const int grid_prep = NBZ + Z + Y + 1;
    hipLaunchKernelGGL(k_prep, dim3(grid_prep), dim3(256), 0, stream,
                       x2y, z2y, y2z, z, x, dotx, nw2, valz, nz2, nry, xn2, cnti, X, Y, Z);
    hipLaunchKernelGGL(k_combine, dim3(Y / CHUNK), dim3(NTL), 0, stream,
                       agey, thr, dotx, nw2, valz, nz2, xn2,
                       ypl, cAl, sl, agl, thl, chv, chi, chcv, chci, cnti);
    hipLaunchKernelGGL(k_loop, dim3(1), dim3(64), 0, stream,
                       z, pit, y2z, agez, nry,
                       ypl, cAl, sl, agl, thl,
                       chv, chi, chcv, chci, cnti, out, Y, Z);
}